// Round 1
// baseline (5198.659 us; speedup 1.0000x reference)
//
#include <hip/hip_runtime.h>
#include <cstdint>
#include <cstddef>

#define N_ROWS 8192
#define DIM    256
#define VCB    20000
#define LLM    4096
#define NCHUNK 16
#define TILES2 157   // ceil(20000/128)

// ---- workspace layout (float elements) ----
#define OFF_MAPPED   0ull            // 20000*256 = 5,120,000
#define OFF_CBSQ     5120000ull      // 20000
#define OFF_PARTD    5140032ull      // 8192*16*16 = 2,097,152
#define OFF_PARTI    7237184ull      // 2,097,152 (ints)
#define OFF_MERGED_D 9334336ull      // 8192*16 = 131,072
#define OFF_MERGED_I 9465408ull      // 131,072 (ints)
#define OFF_FLAT     9596480ull      // 8192 (ints)
#define OFF_LOSSP    9604672ull      // 1024

// ---- output layout (float elements) ----
#define OUT0_OFF 0ull         // z_q_st 8192*256
#define LOSS_OFF 2097152ull   // scalar
#define OUT2_OFF 2097153ull   // token gather 8192
#define OUT3_OFF 2105345ull   // token_to_quantize 8192*256

// sorted ascending lexicographic (dist, idx) top-16 insertion, fully unrolled
__device__ __forceinline__ void topk_insert(float s, int idx, float (&td)[16], int (&ti)[16]) {
  bool gate = (s < td[15]) || (s == td[15] && idx < ti[15]);
  if (gate) {
    float cd = s; int ci = idx;
#pragma unroll
    for (int q = 0; q < 16; ++q) {
      bool less = (cd < td[q]) || (cd == td[q] && ci < ti[q]);
      float od = td[q]; int oi = ti[q];
      if (less) { td[q] = cd; ti[q] = ci; cd = od; ci = oi; }
    }
  }
}

// Kernel 1: mapped[v][d] = sum_k codebook[v][k]*W_map[d][k] + b_map[d]
__global__ __launch_bounds__(256, 3) void gemm1_kernel(
    const float* __restrict__ A, const float* __restrict__ Wm,
    const float* __restrict__ bmap, float* __restrict__ mapped) {
  __shared__ float As[128][33];
  __shared__ float Bs[128][33];
  const int tid = threadIdx.x;
  const int ty = tid >> 4, tx = tid & 15;
  const int v0 = blockIdx.x * 128;
  const int d0 = blockIdx.y * 128;
  float acc[8][8];
#pragma unroll
  for (int i = 0; i < 8; ++i)
#pragma unroll
    for (int j = 0; j < 8; ++j) acc[i][j] = 0.f;

  for (int kc = 0; kc < LLM / 32; ++kc) {
    const int k0 = kc * 32;
    __syncthreads();
#pragma unroll
    for (int t4 = 0; t4 < 4; ++t4) {
      int f = tid + t4 * 256;
      int r = f >> 3;
      int c4 = (f & 7) << 2;
      int av = v0 + r; av = av < VCB ? av : VCB - 1;
      float4 qa = *reinterpret_cast<const float4*>(A + (size_t)av * LLM + k0 + c4);
      As[r][c4 + 0] = qa.x; As[r][c4 + 1] = qa.y; As[r][c4 + 2] = qa.z; As[r][c4 + 3] = qa.w;
      float4 qb = *reinterpret_cast<const float4*>(Wm + (size_t)(d0 + r) * LLM + k0 + c4);
      Bs[r][c4 + 0] = qb.x; Bs[r][c4 + 1] = qb.y; Bs[r][c4 + 2] = qb.z; Bs[r][c4 + 3] = qb.w;
    }
    __syncthreads();
#pragma unroll 4
    for (int kk = 0; kk < 32; ++kk) {
      float za[8], mb[8];
#pragma unroll
      for (int i = 0; i < 8; ++i) za[i] = As[ty * 8 + i][kk];
#pragma unroll
      for (int j = 0; j < 8; ++j) mb[j] = Bs[tx * 8 + j][kk];
#pragma unroll
      for (int i = 0; i < 8; ++i)
#pragma unroll
        for (int j = 0; j < 8; ++j) acc[i][j] = fmaf(za[i], mb[j], acc[i][j]);
    }
  }
#pragma unroll
  for (int i = 0; i < 8; ++i) {
    int v = v0 + ty * 8 + i;
    if (v < VCB) {
#pragma unroll
      for (int j = 0; j < 8; ++j) {
        int d = d0 + tx * 8 + j;
        mapped[(size_t)v * DIM + d] = acc[i][j] + bmap[d];
      }
    }
  }
}

// Kernel 2: cb_sq[v] = sum_d mapped[v][d]^2  (one wave per row)
__global__ void cbsq_kernel(const float* __restrict__ mapped, float* __restrict__ cbsq) {
  const int lane = threadIdx.x & 63;
  const int wid = threadIdx.x >> 6;
  const int row = blockIdx.x * 4 + wid;
  float s = 0.f;
#pragma unroll
  for (int e = 0; e < 4; ++e) {
    float x = mapped[(size_t)row * DIM + lane + e * 64];
    s += x * x;
  }
#pragma unroll
  for (int off = 32; off > 0; off >>= 1) s += __shfl_down(s, off, 64);
  if (lane == 0) cbsq[row] = s;
}

// Kernel 3: fused score GEMM + per-row running top16 over this block's column chunk
__global__ __launch_bounds__(256, 3) void dist_topk_kernel(
    const float* __restrict__ z_e, const float* __restrict__ mapped,
    const float* __restrict__ cbsq, float* __restrict__ part_d, int* __restrict__ part_i) {
  __shared__ float zs[128][33];
  __shared__ float ms[128][33];
  __shared__ float ss[128][33];
  __shared__ float cbs[128];
  const int tid = threadIdx.x;
  const int ty = tid >> 4, tx = tid & 15;
  const int r0 = blockIdx.x * 128;
  const int chunk = blockIdx.y;

  float topd[16]; int topi[16];
#pragma unroll
  for (int q = 0; q < 16; ++q) { topd[q] = __builtin_inff(); topi[q] = 0x7fffffff; }

  for (int t = chunk; t < TILES2; t += NCHUNK) {
    const int c0 = t * 128;
    float acc[8][8];
#pragma unroll
    for (int i = 0; i < 8; ++i)
#pragma unroll
      for (int j = 0; j < 8; ++j) acc[i][j] = 0.f;

    for (int kc = 0; kc < 8; ++kc) {
      __syncthreads();
      if (kc == 0 && tid < 128) {
        int gc = c0 + tid;
        cbs[tid] = (gc < VCB) ? cbsq[gc] : __builtin_inff();
      }
      const int k0 = kc * 32;
#pragma unroll
      for (int t4 = 0; t4 < 4; ++t4) {
        int f = tid + t4 * 256;
        int r = f >> 3;
        int c4 = (f & 7) << 2;
        float4 qz = *reinterpret_cast<const float4*>(z_e + (size_t)(r0 + r) * DIM + k0 + c4);
        zs[r][c4 + 0] = qz.x; zs[r][c4 + 1] = qz.y; zs[r][c4 + 2] = qz.z; zs[r][c4 + 3] = qz.w;
        int cc = c0 + r; cc = cc < VCB ? cc : VCB - 1;
        float4 qm = *reinterpret_cast<const float4*>(mapped + (size_t)cc * DIM + k0 + c4);
        ms[r][c4 + 0] = qm.x; ms[r][c4 + 1] = qm.y; ms[r][c4 + 2] = qm.z; ms[r][c4 + 3] = qm.w;
      }
      __syncthreads();
#pragma unroll 4
      for (int kk = 0; kk < 32; ++kk) {
        float za[8], mb[8];
#pragma unroll
        for (int i = 0; i < 8; ++i) za[i] = zs[ty * 8 + i][kk];
#pragma unroll
        for (int j = 0; j < 8; ++j) mb[j] = ms[tx * 8 + j][kk];
#pragma unroll
        for (int i = 0; i < 8; ++i)
#pragma unroll
          for (int j = 0; j < 8; ++j) acc[i][j] = fmaf(za[i], mb[j], acc[i][j]);
      }
    }
    // epilogue: 4 column groups of 32; score = cb_sq - 2*dot; per-row scan thread updates top16
#pragma unroll
    for (int g = 0; g < 4; ++g) {
      __syncthreads();
      if ((tx >> 2) == g) {
        const int txl = tx & 3;
#pragma unroll
        for (int i = 0; i < 8; ++i)
#pragma unroll
          for (int j = 0; j < 8; ++j)
            ss[ty * 8 + i][txl * 8 + j] = cbs[tx * 8 + j] - 2.0f * acc[i][j];
      }
      __syncthreads();
      if (tid < 128) {
        const int cbase = c0 + g * 32;
#pragma unroll 1
        for (int c = 0; c < 32; ++c) {
          int gc = cbase + c;
          if (gc < VCB) {
            float s = ss[tid][c];
            topk_insert(s, gc, topd, topi);
          }
        }
      }
    }
  }
  if (tid < 128) {
    const size_t row = (size_t)(r0 + tid);
    const size_t base = (row * NCHUNK + chunk) * 16;
#pragma unroll
    for (int q = 0; q < 16; ++q) { part_d[base + q] = topd[q]; part_i[base + q] = topi[q]; }
  }
}

// Kernel 4: merge 16 partial top16s per row -> global sorted top16
__global__ void merge_kernel(const float* __restrict__ part_d, const int* __restrict__ part_i,
                             float* __restrict__ md, int* __restrict__ mi) {
  const int row = blockIdx.x * blockDim.x + threadIdx.x;
  if (row >= N_ROWS) return;
  float topd[16]; int topi[16];
#pragma unroll
  for (int q = 0; q < 16; ++q) { topd[q] = __builtin_inff(); topi[q] = 0x7fffffff; }
  const float* pd = part_d + (size_t)row * (NCHUNK * 16);
  const int* pi = part_i + (size_t)row * (NCHUNK * 16);
#pragma unroll 1
  for (int c = 0; c < NCHUNK * 16; ++c) topk_insert(pd[c], pi[c], topd, topi);
#pragma unroll
  for (int q = 0; q < 16; ++q) {
    md[(size_t)row * 16 + q] = topd[q];
    mi[(size_t)row * 16 + q] = topi[q];
  }
}

// Kernel 5: greedy selection per group of 8 rows (words), banned-set semantics of the reference
__global__ void select_kernel(const int* __restrict__ mi, int* __restrict__ flat) {
  const int g = blockIdx.x * blockDim.x + threadIdx.x;
  if (g >= N_ROWS / 8) return;
  int banned[8];
#pragma unroll
  for (int j = 0; j < 8; ++j) {
    const int row = g * 8 + j;
    const int* cand = mi + (size_t)row * 16;
    int pick = -1;
#pragma unroll
    for (int s = 0; s < 16; ++s) {
      int c = cand[s];
      bool bad = false;
#pragma unroll
      for (int b = 0; b < 8; ++b)
        if (b < j) bad = bad || (banned[b] == c);
      if (pick < 0 && !bad) pick = c;
    }
    banned[j] = pick;
    flat[row] = pick;
  }
}

// Kernel 6: gather outputs + per-block loss partials
__global__ void output_kernel(const float* __restrict__ z_e, const float* __restrict__ mapped,
                              const int* __restrict__ flat, const int* __restrict__ token_id,
                              float* __restrict__ out, float* __restrict__ lossp) {
  const int d = threadIdx.x;
  const int r0 = blockIdx.x * 8;
  float lsum = 0.f;
  float* out0 = out + OUT0_OFF;
  float* out2 = out + OUT2_OFF;
  float* out3 = out + OUT3_OFF;
#pragma unroll 1
  for (int q = 0; q < 8; ++q) {
    const int row = r0 + q;
    const int idx = flat[row];
    float m = mapped[(size_t)idx * DIM + d];
    float ze = z_e[(size_t)row * DIM + d];
    float diff = m - ze;                       // z_q - z_e
    out0[(size_t)row * DIM + d] = ze + diff;   // z_e + (z_q - z_e), literal reference form
    out3[(size_t)row * DIM + d] = ze;          // residual at layer 0 == z_e
    lsum += diff * diff;
    if (d == 0) out2[row] = (float)token_id[idx];
  }
  __shared__ float red[256];
  red[threadIdx.x] = lsum;
  __syncthreads();
  for (int off = 128; off > 0; off >>= 1) {
    if (threadIdx.x < off) red[threadIdx.x] += red[threadIdx.x + off];
    __syncthreads();
  }
  if (threadIdx.x == 0) lossp[blockIdx.x] = red[0];
}

// Kernel 7: final loss reduce; loss = 0.75*L + 0.25*L = mean((z_q - z_e)^2)
__global__ void loss_kernel(const float* __restrict__ lossp, float* __restrict__ out) {
  __shared__ float red[256];
  float s = 0.f;
  for (int i = threadIdx.x; i < 1024; i += 256) s += lossp[i];
  red[threadIdx.x] = s;
  __syncthreads();
  for (int off = 128; off > 0; off >>= 1) {
    if (threadIdx.x < off) red[threadIdx.x] += red[threadIdx.x + off];
    __syncthreads();
  }
  if (threadIdx.x == 0) out[LOSS_OFF] = red[0] * (1.0f / 2097152.0f);
}

extern "C" void kernel_launch(void* const* d_in, const int* in_sizes, int n_in,
                              void* d_out, int out_size, void* d_ws, size_t ws_size,
                              hipStream_t stream) {
  const float* z_e      = (const float*)d_in[0];
  const float* codebook = (const float*)d_in[1];
  const float* Wm       = (const float*)d_in[2];
  const float* bmap     = (const float*)d_in[3];
  const int*   token_id = (const int*)d_in[4];

  float* ws     = (float*)d_ws;
  float* mapped = ws + OFF_MAPPED;
  float* cbsq   = ws + OFF_CBSQ;
  float* part_d = ws + OFF_PARTD;
  int*   part_i = (int*)(ws + OFF_PARTI);
  float* md     = ws + OFF_MERGED_D;
  int*   mi     = (int*)(ws + OFF_MERGED_I);
  int*   flat   = (int*)(ws + OFF_FLAT);
  float* lossp  = ws + OFF_LOSSP;
  float* out    = (float*)d_out;

  gemm1_kernel<<<dim3(TILES2, 2), 256, 0, stream>>>(codebook, Wm, bmap, mapped);
  cbsq_kernel<<<VCB / 4, 256, 0, stream>>>(mapped, cbsq);
  dist_topk_kernel<<<dim3(N_ROWS / 128, NCHUNK), 256, 0, stream>>>(z_e, mapped, cbsq, part_d, part_i);
  merge_kernel<<<N_ROWS / 256, 256, 0, stream>>>(part_d, part_i, md, mi);
  select_kernel<<<4, 256, 0, stream>>>(mi, flat);
  output_kernel<<<N_ROWS / 8, 256, 0, stream>>>(z_e, mapped, flat, token_id, out, lossp);
  loss_kernel<<<1, 256, 0, stream>>>(lossp, out);
}